// Round 1
// baseline (3605.263 us; speedup 1.0000x reference)
//
#include <hip/hip_runtime.h>
#include <math.h>

#define S_LEN 2048
#define D_DIM 1024
#define NH 16
#define DH 64
#define NPOS 512   // 2*SPAN
#define NT (S_LEN / 64)

typedef int   ivec4 __attribute__((ext_vector_type(4)));
typedef int   ivec2 __attribute__((ext_vector_type(2)));
typedef float fvec4 __attribute__((ext_vector_type(4)));

// Raw barrier: only drain LDS (lgkmcnt). Keeps gather/ids VMEM loads in
// flight across the barrier (a full __syncthreads drains vmcnt(0) and
// serializes every random gather into the barrier).
__device__ __forceinline__ void bar_lgkm() {
  asm volatile("s_waitcnt lgkmcnt(0)" ::: "memory");
  __builtin_amdgcn_s_barrier();
}

// ---------------------------------------------------------------------------
// Kernel A: C(M x 1024) = X(M x 1024) @ W(1024 x 1024) + bias, output written
// head-split: out[(h*M + row)*64 + (n&63)] where h = n>>6.
// 128x128 tile, 256 threads, 8x8 per thread, K-step 16. fp32 vector FMA.
// ---------------------------------------------------------------------------
__global__ __launch_bounds__(256) void proj_gemm(
    const float* __restrict__ X, const float* __restrict__ W,
    const float* __restrict__ bias, float* __restrict__ outp, int M) {
  __shared__ float xt[16][132];   // X tile transposed [k][row], pad->132
  __shared__ float wt[16][128];   // W tile straight  [k][col]
  const int tid = threadIdx.x;
  const int br = blockIdx.y, bc = blockIdx.x;
  const int r0 = (tid >> 4) * 8, c0 = (tid & 15) * 8;
  float acc[8][8];
  #pragma unroll
  for (int i = 0; i < 8; i++)
    #pragma unroll
    for (int j = 0; j < 8; j++) acc[i][j] = 0.f;

  const float* Xb = X + (size_t)br * 128 * D_DIM;
  const float* Wb = W + bc * 128;

  for (int k0 = 0; k0 < D_DIM; k0 += 16) {
    __syncthreads();
    #pragma unroll
    for (int i = 0; i < 2; i++) {
      int slot = tid + i * 256;            // 0..511
      int row = slot >> 2;                 // 0..127
      int kc = (slot & 3) * 4;             // 0,4,8,12
      float4 xv = *(const float4*)(Xb + (size_t)row * D_DIM + k0 + kc);
      xt[kc + 0][row] = xv.x; xt[kc + 1][row] = xv.y;
      xt[kc + 2][row] = xv.z; xt[kc + 3][row] = xv.w;
      int kr = slot >> 5;                  // 0..15
      int wc = (slot & 31) * 4;            // 0..124
      *(float4*)&wt[kr][wc] = *(const float4*)(Wb + (size_t)(k0 + kr) * D_DIM + wc);
    }
    __syncthreads();
    #pragma unroll
    for (int kk = 0; kk < 16; kk++) {
      float a[8], b[8];
      *(float4*)&a[0] = *(const float4*)&xt[kk][r0];
      *(float4*)&a[4] = *(const float4*)&xt[kk][r0 + 4];
      *(float4*)&b[0] = *(const float4*)&wt[kk][c0];
      *(float4*)&b[4] = *(const float4*)&wt[kk][c0 + 4];
      #pragma unroll
      for (int ii = 0; ii < 8; ii++)
        #pragma unroll
        for (int jj = 0; jj < 8; jj++)
          acc[ii][jj] = fmaf(a[ii], b[jj], acc[ii][jj]);
    }
  }

  const int n0 = bc * 128 + c0;          // 8 consecutive cols, same head block
  const int h = n0 >> 6, iw = n0 & 63;
  float bvals[8];
  #pragma unroll
  for (int jj = 0; jj < 8; jj++) bvals[jj] = bias[n0 + jj];
  #pragma unroll
  for (int ii = 0; ii < 8; ii++) {
    size_t row = (size_t)br * 128 + r0 + ii;
    float ov[8];
    #pragma unroll
    for (int jj = 0; jj < 8; jj++) ov[jj] = acc[ii][jj] + bvals[jj];
    float* dst = outp + ((size_t)h * M + row) * 64 + iw;
    *(float4*)dst = *(float4*)&ov[0];
    *(float4*)(dst + 4) = *(float4*)&ov[4];
  }
}

// ---------------------------------------------------------------------------
// Kernel B: per-head C(2048 x 512) = A(2048 x 64) @ Bm(512 x 64)^T * inv_scale
// z < 16:  A=q[h],  Bm=pos_k[h] -> c2p ;  z >= 16: A=k[h], Bm=pos_q[h] -> p2c
// ---------------------------------------------------------------------------
__global__ __launch_bounds__(256) void rel_gemm(
    const float* __restrict__ q_ws, const float* __restrict__ k_ws,
    const float* __restrict__ pk_ws, const float* __restrict__ pq_ws,
    float* __restrict__ c2p, float* __restrict__ p2c, float inv_scale) {
  __shared__ float at[16][132];
  __shared__ float bt[16][132];
  const int tid = threadIdx.x;
  const int h = blockIdx.z & 15;
  const int which = blockIdx.z >> 4;
  const float* A = (which ? k_ws : q_ws) + (size_t)h * S_LEN * DH;
  const float* Bm = (which ? pq_ws : pk_ws) + (size_t)h * NPOS * DH;
  float* C = (which ? p2c : c2p) + (size_t)h * S_LEN * NPOS;
  const int br = blockIdx.y, bc = blockIdx.x;
  const int r0 = (tid >> 4) * 8, c0 = (tid & 15) * 8;
  float acc[8][8];
  #pragma unroll
  for (int i = 0; i < 8; i++)
    #pragma unroll
    for (int j = 0; j < 8; j++) acc[i][j] = 0.f;

  for (int k0 = 0; k0 < DH; k0 += 16) {
    __syncthreads();
    #pragma unroll
    for (int i = 0; i < 2; i++) {
      int slot = tid + i * 256;
      int row = slot >> 2;
      int kc = (slot & 3) * 4;
      float4 av = *(const float4*)(A + (size_t)(br * 128 + row) * DH + k0 + kc);
      at[kc + 0][row] = av.x; at[kc + 1][row] = av.y;
      at[kc + 2][row] = av.z; at[kc + 3][row] = av.w;
      float4 bv = *(const float4*)(Bm + (size_t)(bc * 128 + row) * DH + k0 + kc);
      bt[kc + 0][row] = bv.x; bt[kc + 1][row] = bv.y;
      bt[kc + 2][row] = bv.z; bt[kc + 3][row] = bv.w;
    }
    __syncthreads();
    #pragma unroll
    for (int kk = 0; kk < 16; kk++) {
      float a[8], b[8];
      *(float4*)&a[0] = *(const float4*)&at[kk][r0];
      *(float4*)&a[4] = *(const float4*)&at[kk][r0 + 4];
      *(float4*)&b[0] = *(const float4*)&bt[kk][c0];
      *(float4*)&b[4] = *(const float4*)&bt[kk][c0 + 4];
      #pragma unroll
      for (int ii = 0; ii < 8; ii++)
        #pragma unroll
        for (int jj = 0; jj < 8; jj++)
          acc[ii][jj] = fmaf(a[ii], b[jj], acc[ii][jj]);
    }
  }
  #pragma unroll
  for (int ii = 0; ii < 8; ii++) {
    size_t row = (size_t)br * 128 + r0 + ii;
    float ov[8];
    #pragma unroll
    for (int jj = 0; jj < 8; jj++) ov[jj] = acc[ii][jj] * inv_scale;
    float* dst = C + row * NPOS + bc * 128 + c0;
    *(float4*)dst = *(float4*)&ov[0];
    *(float4*)(dst + 4) = *(float4*)&ov[4];
  }
}

// ---------------------------------------------------------------------------
// Kernel C: fused flash attention with gathered disentangled biases.
// 512 threads (8 waves), thread (r4,c4) owns a 2x4 score/output patch of the
// 64x64 tile. ids prefetched one K-tile ahead (registers); gathers issued at
// loop top; raw lgkm-only barriers keep the random gathers in flight across
// the LDS fill so their ~HBM/L3 latency hides under the QK FMA work.
// ids/ids_t are single-use streams -> nontemporal loads so they don't evict
// the 128 MB c2p/p2c tables from L2/LLC (the tables fit in Infinity Cache).
// ---------------------------------------------------------------------------
__global__ __launch_bounds__(512, 4) void attn_kernel(
    const float* __restrict__ q_ws, const float* __restrict__ k_ws,
    const float* __restrict__ v_ws, const float* __restrict__ c2p,
    const float* __restrict__ p2c, const int* __restrict__ ids,
    const int* __restrict__ ids_t, float* __restrict__ outp, float inv_scale) {
  __shared__ float qT[64][68];    // q tile transposed [d][s]
  __shared__ float kT[64][68];    // k tile transposed [d][t]; reused as pT[t][r]
  __shared__ float vS[64][64];    // v tile straight [t][d]
  const int tid = threadIdx.x;
  const int h = blockIdx.y;
  const int s0 = blockIdx.x * 64;
  const int r4 = tid >> 4;        // 0..31
  const int c4 = tid & 15;        // 0..15
  const int r0 = r4 * 2;          // 2 rows per thread
  const int c0 = c4 * 4;          // 4 cols per thread

  const float* qb = q_ws + ((size_t)h * S_LEN + s0) * DH;
  const float* kb = k_ws + (size_t)h * S_LEN * DH;
  const float* vb = v_ws + (size_t)h * S_LEN * DH;
  const int* idc = ids   + (size_t)h * S_LEN * S_LEN;   // [s][t]
  const int* idp = ids_t + (size_t)h * S_LEN * S_LEN;   // [t][s]

  // load q tile transposed (1024 float4 slots over 512 threads)
  #pragma unroll
  for (int i = 0; i < 2; i++) {
    int slot = tid + i * 512;
    int s = slot >> 4;
    int dc = (slot & 15) * 4;
    float4 qv = *(const float4*)(qb + (size_t)s * DH + dc);
    qT[dc + 0][s] = qv.x; qT[dc + 1][s] = qv.y;
    qT[dc + 2][s] = qv.z; qT[dc + 3][s] = qv.w;
  }

  float m[2], l[2], o[2][4];
  #pragma unroll
  for (int ii = 0; ii < 2; ii++) {
    m[ii] = -INFINITY; l[ii] = 0.f;
    #pragma unroll
    for (int jj = 0; jj < 4; jj++) o[ii][jj] = 0.f;
  }

  // prefetch ids for tile 0 (nontemporal: single-use stream)
  ivec4 ia[2];
  ivec2 ib[4];
  #pragma unroll
  for (int ii = 0; ii < 2; ii++)
    ia[ii] = __builtin_nontemporal_load(
        (const ivec4*)(idc + (size_t)(s0 + r0 + ii) * S_LEN + c0));
  #pragma unroll
  for (int jj = 0; jj < 4; jj++)
    ib[jj] = __builtin_nontemporal_load(
        (const ivec2*)(idp + (size_t)(c0 + jj) * S_LEN + s0 + r0));

  for (int kt = 0; kt < NT; kt++) {
    const int t0 = kt * 64;

    // stage k/v into regs (oldest VMEM: consumed first at the LDS fill)
    float4 kreg[2], vreg[2];
    int ts[2], dcs[2];
    #pragma unroll
    for (int i = 0; i < 2; i++) {
      int slot = tid + i * 512;
      ts[i] = slot >> 4;
      dcs[i] = (slot & 15) * 4;
      kreg[i] = *(const float4*)(kb + (size_t)(t0 + ts[i]) * DH + dcs[i]);
      vreg[i] = *(const float4*)(vb + (size_t)(t0 + ts[i]) * DH + dcs[i]);
    }

    // issue the 16 random gathers for THIS tile (ids already in regs).
    // These stay in flight across the two lgkm barriers + LDS fill + QK.
    float gc[2][4], gp[4][2];
    #pragma unroll
    for (int ii = 0; ii < 2; ii++) {
      gc[ii][0] = c2p[ia[ii][0]]; gc[ii][1] = c2p[ia[ii][1]];
      gc[ii][2] = c2p[ia[ii][2]]; gc[ii][3] = c2p[ia[ii][3]];
    }
    #pragma unroll
    for (int jj = 0; jj < 4; jj++) {
      gp[jj][0] = p2c[ib[jj][0]];
      gp[jj][1] = p2c[ib[jj][1]];
    }

    bar_lgkm();   // prior PV reads of kT/vS done (covers pre-loop qT writes too)
    #pragma unroll
    for (int i = 0; i < 2; i++) {
      kT[dcs[i] + 0][ts[i]] = kreg[i].x; kT[dcs[i] + 1][ts[i]] = kreg[i].y;
      kT[dcs[i] + 2][ts[i]] = kreg[i].z; kT[dcs[i] + 3][ts[i]] = kreg[i].w;
      *(float4*)&vS[ts[i]][dcs[i]] = vreg[i];
    }
    bar_lgkm();

    // QK^T mini-GEMM: sc[2][4]
    float sc[2][4];
    #pragma unroll
    for (int ii = 0; ii < 2; ii++)
      #pragma unroll
      for (int jj = 0; jj < 4; jj++) sc[ii][jj] = 0.f;
    #pragma unroll 8
    for (int d = 0; d < 64; d++) {
      float a[2], b[4];
      *(float2*)a = *(const float2*)&qT[d][r0];
      *(float4*)b = *(const float4*)&kT[d][c0];
      #pragma unroll
      for (int ii = 0; ii < 2; ii++)
        #pragma unroll
        for (int jj = 0; jj < 4; jj++)
          sc[ii][jj] = fmaf(a[ii], b[jj], sc[ii][jj]);
    }

    // prefetch ids for NEXT tile (hidden under bias-consume + softmax + PV)
    if (kt + 1 < NT) {
      #pragma unroll
      for (int ii = 0; ii < 2; ii++)
        ia[ii] = __builtin_nontemporal_load(
            (const ivec4*)(idc + (size_t)(s0 + r0 + ii) * S_LEN + t0 + 64 + c0));
      #pragma unroll
      for (int jj = 0; jj < 4; jj++)
        ib[jj] = __builtin_nontemporal_load(
            (const ivec2*)(idp + (size_t)(t0 + 64 + c0 + jj) * S_LEN + s0 + r0));
    }

    // scale + gathered biases (first point that waits on the gathers)
    #pragma unroll
    for (int ii = 0; ii < 2; ii++)
      #pragma unroll
      for (int jj = 0; jj < 4; jj++)
        sc[ii][jj] = fmaf(sc[ii][jj], inv_scale, gc[ii][jj] + gp[jj][ii]);

    // online softmax (rows owned by the 16 lanes sharing r4; reduce over c4)
    #pragma unroll
    for (int ii = 0; ii < 2; ii++) {
      float v = fmaxf(fmaxf(sc[ii][0], sc[ii][1]), fmaxf(sc[ii][2], sc[ii][3]));
      v = fmaxf(v, __shfl_xor(v, 1));
      v = fmaxf(v, __shfl_xor(v, 2));
      v = fmaxf(v, __shfl_xor(v, 4));
      v = fmaxf(v, __shfl_xor(v, 8));
      float mn = fmaxf(m[ii], v);
      float alpha = __expf(m[ii] - mn);
      m[ii] = mn;
      float rs = 0.f;
      #pragma unroll
      for (int jj = 0; jj < 4; jj++) {
        sc[ii][jj] = __expf(sc[ii][jj] - mn);
        rs += sc[ii][jj];
      }
      rs += __shfl_xor(rs, 1);
      rs += __shfl_xor(rs, 2);
      rs += __shfl_xor(rs, 4);
      rs += __shfl_xor(rs, 8);
      l[ii] = l[ii] * alpha + rs;
      #pragma unroll
      for (int jj = 0; jj < 4; jj++) o[ii][jj] *= alpha;
    }

    bar_lgkm();   // all QK reads of kT done -> safe to overwrite with pT
    #pragma unroll
    for (int jj = 0; jj < 4; jj++) {
      float pv[2] = {sc[0][jj], sc[1][jj]};
      *(float2*)&kT[c0 + jj][r0] = *(float2*)pv;   // pT[t][r]
    }
    bar_lgkm();

    // PV mini-GEMM: o[r][d] += sum_t pT[t][r] * vS[t][d]
    #pragma unroll 8
    for (int t = 0; t < 64; t++) {
      float a[2], b[4];
      *(float2*)a = *(const float2*)&kT[t][r0];
      *(float4*)b = *(const float4*)&vS[t][c0];
      #pragma unroll
      for (int ii = 0; ii < 2; ii++)
        #pragma unroll
        for (int jj = 0; jj < 4; jj++)
          o[ii][jj] = fmaf(a[ii], b[jj], o[ii][jj]);
    }
  }

  // epilogue: out (B,S,D) with D = h*64 + d (nontemporal: write-once stream)
  #pragma unroll
  for (int ii = 0; ii < 2; ii++) {
    float inv_l = 1.0f / l[ii];
    fvec4 ov;
    #pragma unroll
    for (int jj = 0; jj < 4; jj++) ov[jj] = o[ii][jj] * inv_l;
    float* dst = outp + (size_t)(s0 + r0 + ii) * D_DIM + h * DH + c0;
    __builtin_nontemporal_store(ov, (fvec4*)dst);
  }
}

// ---------------------------------------------------------------------------
extern "C" void kernel_launch(void* const* d_in, const int* in_sizes, int n_in,
                              void* d_out, int out_size, void* d_ws, size_t ws_size,
                              hipStream_t stream) {
  const float* hs  = (const float*)d_in[0];
  const float* rel = (const float*)d_in[1];
  const float* Wq  = (const float*)d_in[2];
  const float* bq  = (const float*)d_in[3];
  const float* Wk  = (const float*)d_in[4];
  const float* bk  = (const float*)d_in[5];
  const float* Wv  = (const float*)d_in[6];
  const float* bv  = (const float*)d_in[7];
  const int* ids   = (const int*)d_in[8];
  const int* ids_t = (const int*)d_in[9];
  float* outp = (float*)d_out;

  float* ws = (float*)d_ws;
  float* q_ws  = ws;                         // 16*2048*64 = 2097152
  float* k_ws  = q_ws + 2097152;
  float* v_ws  = k_ws + 2097152;
  float* pk_ws = v_ws + 2097152;             // 16*512*64 = 524288
  float* pq_ws = pk_ws + 524288;
  float* c2p_ws = pq_ws + 524288;            // 16*2048*512 = 16777216
  float* p2c_ws = c2p_ws + 16777216;         // total ~156 MB

  const float inv_scale = 1.0f / sqrtf((float)(DH * 3));

  dim3 blk(256);
  proj_gemm<<<dim3(8, 16), blk, 0, stream>>>(hs, Wq, bq, q_ws, S_LEN);
  proj_gemm<<<dim3(8, 16), blk, 0, stream>>>(hs, Wk, bk, k_ws, S_LEN);
  proj_gemm<<<dim3(8, 16), blk, 0, stream>>>(hs, Wv, bv, v_ws, S_LEN);
  proj_gemm<<<dim3(8, 4),  blk, 0, stream>>>(rel, Wk, bk, pk_ws, NPOS);
  proj_gemm<<<dim3(8, 4),  blk, 0, stream>>>(rel, Wq, bq, pq_ws, NPOS);
  rel_gemm<<<dim3(4, 16, 32), blk, 0, stream>>>(q_ws, k_ws, pk_ws, pq_ws,
                                                c2p_ws, p2c_ws, inv_scale);
  attn_kernel<<<dim3(32, 16), dim3(512), 0, stream>>>(
      q_ws, k_ws, v_ws, c2p_ws, p2c_ws, ids, ids_t, outp, inv_scale);
}

// Round 2
// 3163.174 us; speedup vs baseline: 1.1398x; 1.1398x over previous
//
#include <hip/hip_runtime.h>
#include <math.h>

#define S_LEN 2048
#define D_DIM 1024
#define NH 16
#define DH 64
#define NPOS 512   // 2*SPAN
#define NT (S_LEN / 64)

typedef int   ivec4 __attribute__((ext_vector_type(4)));
typedef int   ivec2 __attribute__((ext_vector_type(2)));
typedef float fvec4 __attribute__((ext_vector_type(4)));

// Raw barrier: only drain LDS (lgkmcnt). Keeps VMEM loads in flight across
// the barrier (a full __syncthreads drains vmcnt(0) and serializes every
// in-flight prefetch/gather into the barrier).
__device__ __forceinline__ void bar_lgkm() {
  asm volatile("s_waitcnt lgkmcnt(0)" ::: "memory");
  __builtin_amdgcn_s_barrier();
}

// ---------------------------------------------------------------------------
// Kernel A (merged): all 5 projection GEMMs in one launch, z selects matrix.
// z=0: q = hs@Wq   z=1: k = hs@Wk   z=2: v = hs@Wv   (M=2048)
// z=3: pk = rel@Wk z=4: pq = rel@Wq                  (M=512, by<4 only)
// C(M x 1024) = X @ W + bias, output head-split: out[(h*M+row)*64 + (n&63)].
// 128x128 tile, 256 threads, 8x8/thread, K-step 16.
// Register-prefetch next K-tile + ping-pong LDS -> ONE lgkm barrier per step,
// global-load latency hidden under the 16x64 FMA block.
// ---------------------------------------------------------------------------
__global__ __launch_bounds__(256) void proj_gemm5(
    const float* __restrict__ hs, const float* __restrict__ rel,
    const float* __restrict__ Wq, const float* __restrict__ bq,
    const float* __restrict__ Wk, const float* __restrict__ bk,
    const float* __restrict__ Wv, const float* __restrict__ bv,
    float* __restrict__ q_ws, float* __restrict__ k_ws,
    float* __restrict__ v_ws, float* __restrict__ pk_ws,
    float* __restrict__ pq_ws) {
  const int z = blockIdx.z;
  const float* X; const float* W; const float* bias; float* outp; int M;
  switch (z) {
    case 0:  X = hs;  W = Wq; bias = bq; outp = q_ws;  M = S_LEN; break;
    case 1:  X = hs;  W = Wk; bias = bk; outp = k_ws;  M = S_LEN; break;
    case 2:  X = hs;  W = Wv; bias = bv; outp = v_ws;  M = S_LEN; break;
    case 3:  X = rel; W = Wk; bias = bk; outp = pk_ws; M = NPOS;  break;
    default: X = rel; W = Wq; bias = bq; outp = pq_ws; M = NPOS;  break;
  }
  const int br = blockIdx.y, bc = blockIdx.x;
  if (br * 128 >= M) return;   // pos matrices only need by<4

  __shared__ float xt[2][16][132];   // X tile transposed [k][row], pad->132
  __shared__ float wt[2][16][128];   // W tile straight  [k][col]
  const int tid = threadIdx.x;
  const int r0 = (tid >> 4) * 8, c0 = (tid & 15) * 8;
  float acc[8][8];
  #pragma unroll
  for (int i = 0; i < 8; i++)
    #pragma unroll
    for (int j = 0; j < 8; j++) acc[i][j] = 0.f;

  const float* Xb = X + (size_t)br * 128 * D_DIM;
  const float* Wb = W + bc * 128;

  // fixed per-thread staging coordinates (2 slots each for X and W tiles)
  int row_[2], kc_[2], kr_[2], wc_[2];
  #pragma unroll
  for (int i = 0; i < 2; i++) {
    int slot = tid + i * 256;            // 0..511
    row_[i] = slot >> 2;                 // 0..127
    kc_[i] = (slot & 3) * 4;             // 0,4,8,12
    kr_[i] = slot >> 5;                  // 0..15
    wc_[i] = (slot & 31) * 4;            // 0..124
  }

  // prologue: load K-tile 0 into registers
  float4 xv[2], wv[2];
  #pragma unroll
  for (int i = 0; i < 2; i++) {
    xv[i] = *(const float4*)(Xb + (size_t)row_[i] * D_DIM + kc_[i]);
    wv[i] = *(const float4*)(Wb + (size_t)kr_[i] * D_DIM + wc_[i]);
  }

  for (int k0 = 0; k0 < D_DIM; k0 += 16) {
    const int buf = (k0 >> 4) & 1;
    // commit staged registers to this step's LDS buffer
    #pragma unroll
    for (int i = 0; i < 2; i++) {
      xt[buf][kc_[i] + 0][row_[i]] = xv[i].x;
      xt[buf][kc_[i] + 1][row_[i]] = xv[i].y;
      xt[buf][kc_[i] + 2][row_[i]] = xv[i].z;
      xt[buf][kc_[i] + 3][row_[i]] = xv[i].w;
      *(float4*)&wt[buf][kr_[i]][wc_[i]] = wv[i];
    }
    bar_lgkm();
    // issue next K-tile loads; latency hides under the FMA block below
    if (k0 + 16 < D_DIM) {
      #pragma unroll
      for (int i = 0; i < 2; i++) {
        xv[i] = *(const float4*)(Xb + (size_t)row_[i] * D_DIM + k0 + 16 + kc_[i]);
        wv[i] = *(const float4*)(Wb + (size_t)(k0 + 16 + kr_[i]) * D_DIM + wc_[i]);
      }
    }
    #pragma unroll
    for (int kk = 0; kk < 16; kk++) {
      float a[8], b[8];
      *(float4*)&a[0] = *(const float4*)&xt[buf][kk][r0];
      *(float4*)&a[4] = *(const float4*)&xt[buf][kk][r0 + 4];
      *(float4*)&b[0] = *(const float4*)&wt[buf][kk][c0];
      *(float4*)&b[4] = *(const float4*)&wt[buf][kk][c0 + 4];
      #pragma unroll
      for (int ii = 0; ii < 8; ii++)
        #pragma unroll
        for (int jj = 0; jj < 8; jj++)
          acc[ii][jj] = fmaf(a[ii], b[jj], acc[ii][jj]);
    }
    bar_lgkm();   // all reads of buf done before it is overwritten (2 steps on)
  }

  const int n0 = bc * 128 + c0;          // 8 consecutive cols, same head block
  const int h = n0 >> 6, iw = n0 & 63;
  float bvals[8];
  #pragma unroll
  for (int jj = 0; jj < 8; jj++) bvals[jj] = bias[n0 + jj];
  #pragma unroll
  for (int ii = 0; ii < 8; ii++) {
    size_t row = (size_t)br * 128 + r0 + ii;
    float ov[8];
    #pragma unroll
    for (int jj = 0; jj < 8; jj++) ov[jj] = acc[ii][jj] + bvals[jj];
    float* dst = outp + ((size_t)h * M + row) * 64 + iw;
    *(float4*)dst = *(float4*)&ov[0];
    *(float4*)(dst + 4) = *(float4*)&ov[4];
  }
}

// ---------------------------------------------------------------------------
// Kernel B: per-head C(2048 x 512) = A(2048 x 64) @ Bm(512 x 64)^T * inv_scale
// z < 16:  A=q[h],  Bm=pos_k[h] -> c2p ;  z >= 16: A=k[h], Bm=pos_q[h] -> p2c
// ---------------------------------------------------------------------------
__global__ __launch_bounds__(256) void rel_gemm(
    const float* __restrict__ q_ws, const float* __restrict__ k_ws,
    const float* __restrict__ pk_ws, const float* __restrict__ pq_ws,
    float* __restrict__ c2p, float* __restrict__ p2c, float inv_scale) {
  __shared__ float at[16][132];
  __shared__ float bt[16][132];
  const int tid = threadIdx.x;
  const int h = blockIdx.z & 15;
  const int which = blockIdx.z >> 4;
  const float* A = (which ? k_ws : q_ws) + (size_t)h * S_LEN * DH;
  const float* Bm = (which ? pq_ws : pk_ws) + (size_t)h * NPOS * DH;
  float* C = (which ? p2c : c2p) + (size_t)h * S_LEN * NPOS;
  const int br = blockIdx.y, bc = blockIdx.x;
  const int r0 = (tid >> 4) * 8, c0 = (tid & 15) * 8;
  float acc[8][8];
  #pragma unroll
  for (int i = 0; i < 8; i++)
    #pragma unroll
    for (int j = 0; j < 8; j++) acc[i][j] = 0.f;

  for (int k0 = 0; k0 < DH; k0 += 16) {
    __syncthreads();
    #pragma unroll
    for (int i = 0; i < 2; i++) {
      int slot = tid + i * 256;
      int row = slot >> 2;
      int kc = (slot & 3) * 4;
      float4 av = *(const float4*)(A + (size_t)(br * 128 + row) * DH + k0 + kc);
      at[kc + 0][row] = av.x; at[kc + 1][row] = av.y;
      at[kc + 2][row] = av.z; at[kc + 3][row] = av.w;
      float4 bv = *(const float4*)(Bm + (size_t)(bc * 128 + row) * DH + k0 + kc);
      bt[kc + 0][row] = bv.x; bt[kc + 1][row] = bv.y;
      bt[kc + 2][row] = bv.z; bt[kc + 3][row] = bv.w;
    }
    __syncthreads();
    #pragma unroll
    for (int kk = 0; kk < 16; kk++) {
      float a[8], b[8];
      *(float4*)&a[0] = *(const float4*)&at[kk][r0];
      *(float4*)&a[4] = *(const float4*)&at[kk][r0 + 4];
      *(float4*)&b[0] = *(const float4*)&bt[kk][c0];
      *(float4*)&b[4] = *(const float4*)&bt[kk][c0 + 4];
      #pragma unroll
      for (int ii = 0; ii < 8; ii++)
        #pragma unroll
        for (int jj = 0; jj < 8; jj++)
          acc[ii][jj] = fmaf(a[ii], b[jj], acc[ii][jj]);
    }
  }
  #pragma unroll
  for (int ii = 0; ii < 8; ii++) {
    size_t row = (size_t)br * 128 + r0 + ii;
    float ov[8];
    #pragma unroll
    for (int jj = 0; jj < 8; jj++) ov[jj] = acc[ii][jj] * inv_scale;
    float* dst = C + row * NPOS + bc * 128 + c0;
    *(float4*)dst = *(float4*)&ov[0];
    *(float4*)(dst + 4) = *(float4*)&ov[4];
  }
}

// ---------------------------------------------------------------------------
// Kernel C: fused flash attention with gathered disentangled biases.
// (unchanged from round 1 — the gather wall is the random-64B miss-path
// throughput ceiling: 134M lines ~= 8.6 GB at ~3.5 TB/s ~= 2.48 ms.)
// ---------------------------------------------------------------------------
__global__ __launch_bounds__(512, 4) void attn_kernel(
    const float* __restrict__ q_ws, const float* __restrict__ k_ws,
    const float* __restrict__ v_ws, const float* __restrict__ c2p,
    const float* __restrict__ p2c, const int* __restrict__ ids,
    const int* __restrict__ ids_t, float* __restrict__ outp, float inv_scale) {
  __shared__ float qT[64][68];    // q tile transposed [d][s]
  __shared__ float kT[64][68];    // k tile transposed [d][t]; reused as pT[t][r]
  __shared__ float vS[64][64];    // v tile straight [t][d]
  const int tid = threadIdx.x;
  const int h = blockIdx.y;
  const int s0 = blockIdx.x * 64;
  const int r4 = tid >> 4;        // 0..31
  const int c4 = tid & 15;        // 0..15
  const int r0 = r4 * 2;          // 2 rows per thread
  const int c0 = c4 * 4;          // 4 cols per thread

  const float* qb = q_ws + ((size_t)h * S_LEN + s0) * DH;
  const float* kb = k_ws + (size_t)h * S_LEN * DH;
  const float* vb = v_ws + (size_t)h * S_LEN * DH;
  const int* idc = ids   + (size_t)h * S_LEN * S_LEN;   // [s][t]
  const int* idp = ids_t + (size_t)h * S_LEN * S_LEN;   // [t][s]

  // load q tile transposed (1024 float4 slots over 512 threads)
  #pragma unroll
  for (int i = 0; i < 2; i++) {
    int slot = tid + i * 512;
    int s = slot >> 4;
    int dc = (slot & 15) * 4;
    float4 qv = *(const float4*)(qb + (size_t)s * DH + dc);
    qT[dc + 0][s] = qv.x; qT[dc + 1][s] = qv.y;
    qT[dc + 2][s] = qv.z; qT[dc + 3][s] = qv.w;
  }

  float m[2], l[2], o[2][4];
  #pragma unroll
  for (int ii = 0; ii < 2; ii++) {
    m[ii] = -INFINITY; l[ii] = 0.f;
    #pragma unroll
    for (int jj = 0; jj < 4; jj++) o[ii][jj] = 0.f;
  }

  // prefetch ids for tile 0 (nontemporal: single-use stream)
  ivec4 ia[2];
  ivec2 ib[4];
  #pragma unroll
  for (int ii = 0; ii < 2; ii++)
    ia[ii] = __builtin_nontemporal_load(
        (const ivec4*)(idc + (size_t)(s0 + r0 + ii) * S_LEN + c0));
  #pragma unroll
  for (int jj = 0; jj < 4; jj++)
    ib[jj] = __builtin_nontemporal_load(
        (const ivec2*)(idp + (size_t)(c0 + jj) * S_LEN + s0 + r0));

  for (int kt = 0; kt < NT; kt++) {
    const int t0 = kt * 64;

    // stage k/v into regs (oldest VMEM: consumed first at the LDS fill)
    float4 kreg[2], vreg[2];
    int ts[2], dcs[2];
    #pragma unroll
    for (int i = 0; i < 2; i++) {
      int slot = tid + i * 512;
      ts[i] = slot >> 4;
      dcs[i] = (slot & 15) * 4;
      kreg[i] = *(const float4*)(kb + (size_t)(t0 + ts[i]) * DH + dcs[i]);
      vreg[i] = *(const float4*)(vb + (size_t)(t0 + ts[i]) * DH + dcs[i]);
    }

    // issue the 16 random gathers for THIS tile (ids already in regs).
    float gc[2][4], gp[4][2];
    #pragma unroll
    for (int ii = 0; ii < 2; ii++) {
      gc[ii][0] = c2p[ia[ii][0]]; gc[ii][1] = c2p[ia[ii][1]];
      gc[ii][2] = c2p[ia[ii][2]]; gc[ii][3] = c2p[ia[ii][3]];
    }
    #pragma unroll
    for (int jj = 0; jj < 4; jj++) {
      gp[jj][0] = p2c[ib[jj][0]];
      gp[jj][1] = p2c[ib[jj][1]];
    }

    bar_lgkm();   // prior PV reads of kT/vS done (covers pre-loop qT writes too)
    #pragma unroll
    for (int i = 0; i < 2; i++) {
      kT[dcs[i] + 0][ts[i]] = kreg[i].x; kT[dcs[i] + 1][ts[i]] = kreg[i].y;
      kT[dcs[i] + 2][ts[i]] = kreg[i].z; kT[dcs[i] + 3][ts[i]] = kreg[i].w;
      *(float4*)&vS[ts[i]][dcs[i]] = vreg[i];
    }
    bar_lgkm();

    // QK^T mini-GEMM: sc[2][4]
    float sc[2][4];
    #pragma unroll
    for (int ii = 0; ii < 2; ii++)
      #pragma unroll
      for (int jj = 0; jj < 4; jj++) sc[ii][jj] = 0.f;
    #pragma unroll 8
    for (int d = 0; d < 64; d++) {
      float a[2], b[4];
      *(float2*)a = *(const float2*)&qT[d][r0];
      *(float4*)b = *(const float4*)&kT[d][c0];
      #pragma unroll
      for (int ii = 0; ii < 2; ii++)
        #pragma unroll
        for (int jj = 0; jj < 4; jj++)
          sc[ii][jj] = fmaf(a[ii], b[jj], sc[ii][jj]);
    }

    // prefetch ids for NEXT tile (hidden under bias-consume + softmax + PV)
    if (kt + 1 < NT) {
      #pragma unroll
      for (int ii = 0; ii < 2; ii++)
        ia[ii] = __builtin_nontemporal_load(
            (const ivec4*)(idc + (size_t)(s0 + r0 + ii) * S_LEN + t0 + 64 + c0));
      #pragma unroll
      for (int jj = 0; jj < 4; jj++)
        ib[jj] = __builtin_nontemporal_load(
            (const ivec2*)(idp + (size_t)(t0 + 64 + c0 + jj) * S_LEN + s0 + r0));
    }

    // scale + gathered biases (first point that waits on the gathers)
    #pragma unroll
    for (int ii = 0; ii < 2; ii++)
      #pragma unroll
      for (int jj = 0; jj < 4; jj++)
        sc[ii][jj] = fmaf(sc[ii][jj], inv_scale, gc[ii][jj] + gp[jj][ii]);

    // online softmax (rows owned by the 16 lanes sharing r4; reduce over c4)
    #pragma unroll
    for (int ii = 0; ii < 2; ii++) {
      float v = fmaxf(fmaxf(sc[ii][0], sc[ii][1]), fmaxf(sc[ii][2], sc[ii][3]));
      v = fmaxf(v, __shfl_xor(v, 1));
      v = fmaxf(v, __shfl_xor(v, 2));
      v = fmaxf(v, __shfl_xor(v, 4));
      v = fmaxf(v, __shfl_xor(v, 8));
      float mn = fmaxf(m[ii], v);
      float alpha = __expf(m[ii] - mn);
      m[ii] = mn;
      float rs = 0.f;
      #pragma unroll
      for (int jj = 0; jj < 4; jj++) {
        sc[ii][jj] = __expf(sc[ii][jj] - mn);
        rs += sc[ii][jj];
      }
      rs += __shfl_xor(rs, 1);
      rs += __shfl_xor(rs, 2);
      rs += __shfl_xor(rs, 4);
      rs += __shfl_xor(rs, 8);
      l[ii] = l[ii] * alpha + rs;
      #pragma unroll
      for (int jj = 0; jj < 4; jj++) o[ii][jj] *= alpha;
    }

    bar_lgkm();   // all QK reads of kT done -> safe to overwrite with pT
    #pragma unroll
    for (int jj = 0; jj < 4; jj++) {
      float pv[2] = {sc[0][jj], sc[1][jj]};
      *(float2*)&kT[c0 + jj][r0] = *(float2*)pv;   // pT[t][r]
    }
    bar_lgkm();

    // PV mini-GEMM: o[r][d] += sum_t pT[t][r] * vS[t][d]
    #pragma unroll 8
    for (int t = 0; t < 64; t++) {
      float a[2], b[4];
      *(float2*)a = *(const float2*)&kT[t][r0];
      *(float4*)b = *(const float4*)&vS[t][c0];
      #pragma unroll
      for (int ii = 0; ii < 2; ii++)
        #pragma unroll
        for (int jj = 0; jj < 4; jj++)
          o[ii][jj] = fmaf(a[ii], b[jj], o[ii][jj]);
    }
  }

  // epilogue: out (B,S,D) with D = h*64 + d (nontemporal: write-once stream)
  #pragma unroll
  for (int ii = 0; ii < 2; ii++) {
    float inv_l = 1.0f / l[ii];
    fvec4 ov;
    #pragma unroll
    for (int jj = 0; jj < 4; jj++) ov[jj] = o[ii][jj] * inv_l;
    float* dst = outp + (size_t)(s0 + r0 + ii) * D_DIM + h * DH + c0;
    __builtin_nontemporal_store(ov, (fvec4*)dst);
  }
}

// ---------------------------------------------------------------------------
extern "C" void kernel_launch(void* const* d_in, const int* in_sizes, int n_in,
                              void* d_out, int out_size, void* d_ws, size_t ws_size,
                              hipStream_t stream) {
  const float* hs  = (const float*)d_in[0];
  const float* rel = (const float*)d_in[1];
  const float* Wq  = (const float*)d_in[2];
  const float* bq  = (const float*)d_in[3];
  const float* Wk  = (const float*)d_in[4];
  const float* bk  = (const float*)d_in[5];
  const float* Wv  = (const float*)d_in[6];
  const float* bv  = (const float*)d_in[7];
  const int* ids   = (const int*)d_in[8];
  const int* ids_t = (const int*)d_in[9];
  float* outp = (float*)d_out;

  float* ws = (float*)d_ws;
  float* q_ws  = ws;                         // 16*2048*64 = 2097152
  float* k_ws  = q_ws + 2097152;
  float* v_ws  = k_ws + 2097152;
  float* pk_ws = v_ws + 2097152;             // 16*512*64 = 524288
  float* pq_ws = pk_ws + 524288;
  float* c2p_ws = pq_ws + 524288;            // 16*2048*512 = 16777216
  float* p2c_ws = c2p_ws + 16777216;         // total ~156 MB

  const float inv_scale = 1.0f / sqrtf((float)(DH * 3));

  proj_gemm5<<<dim3(8, 16, 5), dim3(256), 0, stream>>>(
      hs, rel, Wq, bq, Wk, bk, Wv, bv, q_ws, k_ws, v_ws, pk_ws, pq_ws);
  rel_gemm<<<dim3(4, 16, 32), dim3(256), 0, stream>>>(
      q_ws, k_ws, pk_ws, pq_ws, c2p_ws, p2c_ws, inv_scale);
  attn_kernel<<<dim3(32, 16), dim3(512), 0, stream>>>(
      q_ws, k_ws, v_ws, c2p_ws, p2c_ws, ids, ids_t, outp, inv_scale);
}